// Round 2
// baseline (245.933 us; speedup 1.0000x reference)
//
#include <hip/hip_runtime.h>
#include <math.h>

#define DFEAT   128
#define KSPLIT  16      // pass1 blocks per segment
#define GROUPS  8       // 256 threads / 32-lane groups
#define NEG_INF (-INFINITY)

// ---------------------------------------------------------------------------
// Fused kernel: grid = B*KSPLIT pass1 blocks + (B*KSPLIT)/2 zero-fill blocks,
// interleaved 2:1 so both roles co-schedule across CUs.
//   role fill  (i%3==2): zero d_out rows [B, V)  (write-only stream)
//   role pass1 (else)  : online-softmax partial over slice j of segment b
// Segment bounds are computed inline by binary search over the sorted
// batch_index (uniform across the block -> broadcast loads, L1/L2 cached).
// ---------------------------------------------------------------------------
__global__ __launch_bounds__(256) void fused_kernel(
    const float* __restrict__ node_feats,
    const float* __restrict__ Q,
    const int*   __restrict__ bidx,
    int V, int B, int zblocks,
    float* __restrict__ H,
    float* __restrict__ M, float* __restrict__ Zp, float* __restrict__ NUM)
{
    const int i = blockIdx.x;

    if (i % 3 == 2) {
        // ---------------- zero-fill role: rows [B, V) ----------------
        const int fb = i / 3;
        float4* dst = (float4*)(H + (size_t)B * DFEAT);
        const size_t n4     = ((size_t)(V - B) * DFEAT) >> 2;
        const size_t stride = (size_t)zblocks * 256;
        const float4 z = {0.f, 0.f, 0.f, 0.f};
        for (size_t k = (size_t)fb * 256 + threadIdx.x; k < n4; k += stride)
            dst[k] = z;
        return;
    }

    // ---------------- pass1 role ----------------
    const int blk  = i - i / 3;          // in [0, B*KSPLIT)
    const int b    = blk / KSPLIT;
    const int j    = blk % KSPLIT;
    const int tid  = threadIdx.x;
    const int g    = tid >> 5;
    const int lane = tid & 31;

    // inline lower_bound for b and b+1 (uniform across block)
    int lo = 0, hi = V;
    while (lo < hi) { int mid = (lo + hi) >> 1; if (bidx[mid] < b) lo = mid + 1; else hi = mid; }
    const int start = lo;
    hi = V;
    while (lo < hi) { int mid = (lo + hi) >> 1; if (bidx[mid] < b + 1) lo = mid + 1; else hi = mid; }
    const int end = lo;

    const int len  = end - start;
    const int my_s = start + (int)(((long long)len * j)       / KSPLIT);
    const int my_e = start + (int)(((long long)len * (j + 1)) / KSPLIT);

    const float4* nf4 = (const float4*)node_feats;
    const float4  q   = ((const float4*)(Q + (size_t)b * DFEAT))[lane];

    float  m = NEG_INF, Z = 0.f;
    float4 num = {0.f, 0.f, 0.f, 0.f};

    for (int v = my_s + g; v < my_e; v += GROUPS) {
        const float4 x = nf4[(size_t)v * (DFEAT / 4) + lane];
        float s = x.x * q.x + x.y * q.y + x.z * q.z + x.w * q.w;
        s += __shfl_xor(s, 1);
        s += __shfl_xor(s, 2);
        s += __shfl_xor(s, 4);
        s += __shfl_xor(s, 8);
        s += __shfl_xor(s, 16);
        s *= 0.08838834764831845f;  // 1/sqrt(128)
        if (s > m) {                 // group-uniform branch
            const float f = __expf(m - s);   // exp(-inf)=0 on first node
            Z *= f;
            num.x *= f; num.y *= f; num.z *= f; num.w *= f;
            m = s;
        }
        const float e = __expf(s - m);
        Z += e;
        num.x += e * x.x; num.y += e * x.y; num.z += e * x.z; num.w += e * x.w;
    }

    // ---- merge 8 group-partials into one block-partial via LDS ----
    __shared__ float gm[GROUPS], gz[GROUPS];
    __shared__ float nm[GROUPS][DFEAT];
    if (lane == 0) { gm[g] = m; gz[g] = Z; }
    __syncthreads();

    float mstar = gm[0];
    #pragma unroll
    for (int k = 1; k < GROUPS; ++k) mstar = fmaxf(mstar, gm[k]);

    const float f = (m == NEG_INF) ? 0.f : __expf(m - mstar);
    nm[g][4 * lane + 0] = num.x * f;
    nm[g][4 * lane + 1] = num.y * f;
    nm[g][4 * lane + 2] = num.z * f;
    nm[g][4 * lane + 3] = num.w * f;
    __syncthreads();

    if (tid < DFEAT) {
        float acc = 0.f;
        #pragma unroll
        for (int k = 0; k < GROUPS; ++k) acc += nm[k][tid];
        NUM[(size_t)blk * DFEAT + tid] = acc;
    }
    if (tid == 0) {
        float Zb = 0.f;
        #pragma unroll
        for (int k = 0; k < GROUPS; ++k) {
            const float fk = (gm[k] == NEG_INF) ? 0.f : __expf(gm[k] - mstar);
            Zb += gz[k] * fk;
        }
        M[blk]  = mstar;   // -inf if slice empty
        Zp[blk] = Zb;
    }
}

// ---------------------------------------------------------------------------
// pass2: merge the KSPLIT partials of each segment, write H rows [0, B).
// ---------------------------------------------------------------------------
__global__ __launch_bounds__(128) void pass2_kernel(
    const float* __restrict__ M, const float* __restrict__ Zp,
    const float* __restrict__ NUM, float* __restrict__ H)
{
    const int b = blockIdx.x;
    const int d = threadIdx.x;

    float mstar = NEG_INF;
    #pragma unroll
    for (int i = 0; i < KSPLIT; ++i) mstar = fmaxf(mstar, M[b * KSPLIT + i]);

    if (mstar == NEG_INF) {          // empty segment -> zero row
        H[(size_t)b * DFEAT + d] = 0.f;
        return;
    }

    float W = 0.f, acc = 0.f;
    #pragma unroll
    for (int i = 0; i < KSPLIT; ++i) {
        const float mi = M[b * KSPLIT + i];
        const float fi = (mi == NEG_INF) ? 0.f : __expf(mi - mstar);
        W   += Zp[b * KSPLIT + i] * fi;
        acc += NUM[(size_t)(b * KSPLIT + i) * DFEAT + d] * fi;
    }
    H[(size_t)b * DFEAT + d] = acc / W;   // W >= 1 when segment nonempty
}

// ---------------------------------------------------------------------------
extern "C" void kernel_launch(void* const* d_in, const int* in_sizes, int n_in,
                              void* d_out, int out_size, void* d_ws, size_t ws_size,
                              hipStream_t stream) {
    const float* node_feats = (const float*)d_in[0];  // [V, 128]
    const float* Q          = (const float*)d_in[1];  // [B, 128]
    const int*   bidx       = (const int*)  d_in[2];  // [V] sorted
    float*       H          = (float*)d_out;          // [V, 128]

    const int V = in_sizes[2];
    const int B = in_sizes[1] / DFEAT;

    // workspace layout (512B-aligned chunks)
    char* ws = (char*)d_ws;
    size_t off = 0;
    float* M  = (float*)(ws + off);
    off += ((size_t)B * KSPLIT * sizeof(float) + 511) & ~(size_t)511;
    float* Zp = (float*)(ws + off);
    off += ((size_t)B * KSPLIT * sizeof(float) + 511) & ~(size_t)511;
    float* NUM = (float*)(ws + off);

    const int p1blocks = B * KSPLIT;          // 4096
    const int zblocks  = p1blocks / 2;        // 2048 (keeps the %3 mapping exact)

    fused_kernel<<<p1blocks + zblocks, 256, 0, stream>>>(
        node_feats, Q, bidx, V, B, zblocks, H, M, Zp, NUM);
    pass2_kernel<<<B, DFEAT, 0, stream>>>(M, Zp, NUM, H);
}

// Round 3
// 228.923 us; speedup vs baseline: 1.0743x; 1.0743x over previous
//
#include <hip/hip_runtime.h>
#include <math.h>

#define DFEAT   128
#define KSPLIT  16      // blocks per segment
#define NEG_INF (-INFINITY)
#define SCALE   0.08838834764831845f   // 1/sqrt(128)

// sum across the 16-lane group using DPP only (no DS pipe):
// xor1 (quad_perm [1,0,3,2]), xor2 (quad_perm [2,3,0,1]),
// row_half_mirror (pairs 8-halves), row_mirror (pairs 16-halves).
__device__ __forceinline__ float red16(float s) {
    s += __int_as_float(__builtin_amdgcn_update_dpp(0, __float_as_int(s), 0xB1,  0xF, 0xF, true));
    s += __int_as_float(__builtin_amdgcn_update_dpp(0, __float_as_int(s), 0x4E,  0xF, 0xF, true));
    s += __int_as_float(__builtin_amdgcn_update_dpp(0, __float_as_int(s), 0x141, 0xF, 0xF, true));
    s += __int_as_float(__builtin_amdgcn_update_dpp(0, __float_as_int(s), 0x140, 0xF, 0xF, true));
    return s;
}

// ---------------------------------------------------------------------------
// Fused: each of B*KSPLIT blocks streams slice j of segment b (online softmax
// partial) AND writes its share of the zero-fill of H rows [B, V), with the
// zero stores interleaved into the same loop (D2D-copy-like wave-level mix).
// 256 threads = 16 groups of 16 lanes; lane ln owns columns 8*ln..8*ln+7.
// ---------------------------------------------------------------------------
__global__ __launch_bounds__(256) void fused_kernel(
    const float* __restrict__ node_feats,
    const float* __restrict__ Q,
    const int*   __restrict__ bidx,
    int V, int B,
    float* __restrict__ H,
    float* __restrict__ M, float* __restrict__ Zp, float* __restrict__ NUM)
{
    const int blk = blockIdx.x;
    const int b   = blk / KSPLIT;
    const int j   = blk % KSPLIT;
    const int tid = threadIdx.x;
    const int grp = tid >> 4;
    const int ln  = tid & 15;

    // ---- zero-fill bookkeeping (rows [B, V)) ----
    float4* fdst = (float4*)(H + (size_t)B * DFEAT);
    const size_t ftot = ((size_t)(V - B) * DFEAT) >> 2;   // float4 count
    const size_t fstr = (size_t)gridDim.x * 256;
    size_t kf = (size_t)blk * 256 + tid;
    const float4 z4 = {0.f, 0.f, 0.f, 0.f};

    // ---- segment bounds: inline lower_bound (uniform across block) ----
    int lo = 0, hi = V;
    while (lo < hi) { int mid = (lo + hi) >> 1; if (bidx[mid] < b) lo = mid + 1; else hi = mid; }
    const int start = lo;
    hi = V;
    while (lo < hi) { int mid = (lo + hi) >> 1; if (bidx[mid] < b + 1) lo = mid + 1; else hi = mid; }
    const int end = lo;

    const int len  = end - start;
    const int my_s = start + (int)(((long long)len * j)       / KSPLIT);
    const int my_e = start + (int)(((long long)len * (j + 1)) / KSPLIT);

    const float4* nf = (const float4*)node_feats;
    const float4* qr = (const float4*)(Q + (size_t)b * DFEAT);
    const float4 qa = qr[2 * ln];
    const float4 qb = qr[2 * ln + 1];

    float m = NEG_INF, Z = 0.f;
    float num[8] = {0.f, 0.f, 0.f, 0.f, 0.f, 0.f, 0.f, 0.f};

    int v = my_s + grp;
    for (; v + 16 < my_e; v += 32) {
        const float4* r0 = nf + (size_t)v * (DFEAT / 4) + 2 * ln;
        const float4* r1 = nf + (size_t)(v + 16) * (DFEAT / 4) + 2 * ln;
        const float4 a0 = r0[0], a1 = r0[1];
        const float4 b0 = r1[0], b1 = r1[1];

        // interleaved zero-fill stores (independent of the loads)
        if (kf < ftot) fdst[kf] = z4; kf += fstr;
        if (kf < ftot) fdst[kf] = z4; kf += fstr;
        if (kf < ftot) fdst[kf] = z4; kf += fstr;
        if (kf < ftot) fdst[kf] = z4; kf += fstr;

        float s0 = a0.x*qa.x + a0.y*qa.y + a0.z*qa.z + a0.w*qa.w
                 + a1.x*qb.x + a1.y*qb.y + a1.z*qb.z + a1.w*qb.w;
        float s1 = b0.x*qa.x + b0.y*qa.y + b0.z*qa.z + b0.w*qa.w
                 + b1.x*qb.x + b1.y*qb.y + b1.z*qb.z + b1.w*qb.w;
        s0 = red16(s0) * SCALE;
        s1 = red16(s1) * SCALE;

        const float mn = fmaxf(fmaxf(s0, s1), m);
        const float f  = __expf(m  - mn);   // 1 if no new max; 0 on first (m=-inf)
        const float e0 = __expf(s0 - mn);
        const float e1 = __expf(s1 - mn);
        Z = Z * f + e0 + e1;
        num[0] = num[0]*f + e0*a0.x + e1*b0.x;
        num[1] = num[1]*f + e0*a0.y + e1*b0.y;
        num[2] = num[2]*f + e0*a0.z + e1*b0.z;
        num[3] = num[3]*f + e0*a0.w + e1*b0.w;
        num[4] = num[4]*f + e0*a1.x + e1*b1.x;
        num[5] = num[5]*f + e0*a1.y + e1*b1.y;
        num[6] = num[6]*f + e0*a1.z + e1*b1.z;
        num[7] = num[7]*f + e0*a1.w + e1*b1.w;
        m = mn;
    }
    if (v < my_e) {   // at most one tail node per group
        const float4* r0 = nf + (size_t)v * (DFEAT / 4) + 2 * ln;
        const float4 a0 = r0[0], a1 = r0[1];
        float s = a0.x*qa.x + a0.y*qa.y + a0.z*qa.z + a0.w*qa.w
                + a1.x*qb.x + a1.y*qb.y + a1.z*qb.z + a1.w*qb.w;
        s = red16(s) * SCALE;
        const float mn = fmaxf(s, m);
        const float f  = __expf(m - mn);
        const float e  = __expf(s - mn);
        Z = Z * f + e;
        num[0] = num[0]*f + e*a0.x;  num[1] = num[1]*f + e*a0.y;
        num[2] = num[2]*f + e*a0.z;  num[3] = num[3]*f + e*a0.w;
        num[4] = num[4]*f + e*a1.x;  num[5] = num[5]*f + e*a1.y;
        num[6] = num[6]*f + e*a1.z;  num[7] = num[7]*f + e*a1.w;
        m = mn;
    }
    // drain remaining zero-fill quota
    for (; kf < ftot; kf += fstr) fdst[kf] = z4;

    // ---- merge 16 group-partials (m, Z uniform within each group) ----
    __shared__ float gm[16], gz[16];
    __shared__ float nm[16][DFEAT];
    if (ln == 0) { gm[grp] = m; gz[grp] = Z; }
    __syncthreads();

    float mstar = gm[0];
    #pragma unroll
    for (int k = 1; k < 16; ++k) mstar = fmaxf(mstar, gm[k]);

    const float fs = (m == NEG_INF) ? 0.f : __expf(m - mstar);
    #pragma unroll
    for (int i = 0; i < 8; ++i) nm[grp][ln * 8 + i] = num[i] * fs;
    __syncthreads();

    if (tid < DFEAT) {
        float acc = 0.f;
        #pragma unroll
        for (int k = 0; k < 16; ++k) acc += nm[k][tid];
        NUM[(size_t)blk * DFEAT + tid] = acc;
    }
    if (tid == 0) {
        float Zb = 0.f;
        #pragma unroll
        for (int k = 0; k < 16; ++k) {
            const float fk = (gm[k] == NEG_INF) ? 0.f : __expf(gm[k] - mstar);
            Zb += gz[k] * fk;
        }
        M[blk]  = mstar;   // -inf if slice empty
        Zp[blk] = Zb;
    }
}

// ---------------------------------------------------------------------------
// pass2: merge the KSPLIT partials of each segment, write H rows [0, B).
// ---------------------------------------------------------------------------
__global__ __launch_bounds__(128) void pass2_kernel(
    const float* __restrict__ M, const float* __restrict__ Zp,
    const float* __restrict__ NUM, float* __restrict__ H)
{
    const int b = blockIdx.x;
    const int d = threadIdx.x;

    float mstar = NEG_INF;
    #pragma unroll
    for (int i = 0; i < KSPLIT; ++i) mstar = fmaxf(mstar, M[b * KSPLIT + i]);

    if (mstar == NEG_INF) {          // empty segment -> zero row
        H[(size_t)b * DFEAT + d] = 0.f;
        return;
    }

    float W = 0.f, acc = 0.f;
    #pragma unroll
    for (int i = 0; i < KSPLIT; ++i) {
        const float mi = M[b * KSPLIT + i];
        const float fi = (mi == NEG_INF) ? 0.f : __expf(mi - mstar);
        W   += Zp[b * KSPLIT + i] * fi;
        acc += NUM[(size_t)(b * KSPLIT + i) * DFEAT + d] * fi;
    }
    H[(size_t)b * DFEAT + d] = acc / W;   // W >= 1 when segment nonempty
}

// ---------------------------------------------------------------------------
extern "C" void kernel_launch(void* const* d_in, const int* in_sizes, int n_in,
                              void* d_out, int out_size, void* d_ws, size_t ws_size,
                              hipStream_t stream) {
    const float* node_feats = (const float*)d_in[0];  // [V, 128]
    const float* Q          = (const float*)d_in[1];  // [B, 128]
    const int*   bidx       = (const int*)  d_in[2];  // [V] sorted
    float*       H          = (float*)d_out;          // [V, 128]

    const int V = in_sizes[2];
    const int B = in_sizes[1] / DFEAT;

    // workspace layout (512B-aligned chunks)
    char* ws = (char*)d_ws;
    size_t off = 0;
    float* M  = (float*)(ws + off);
    off += ((size_t)B * KSPLIT * sizeof(float) + 511) & ~(size_t)511;
    float* Zp = (float*)(ws + off);
    off += ((size_t)B * KSPLIT * sizeof(float) + 511) & ~(size_t)511;
    float* NUM = (float*)(ws + off);

    fused_kernel<<<B * KSPLIT, 256, 0, stream>>>(
        node_feats, Q, bidx, V, B, H, M, Zp, NUM);
    pass2_kernel<<<B, DFEAT, 0, stream>>>(M, Zp, NUM, H);
}